// Round 5
// baseline (288.671 us; speedup 1.0000x reference)
//
#include <hip/hip_runtime.h>

#define HD 64   // hidden dim D

// ---- degree histogram (int) ----
__global__ void deg_kernel(const int* __restrict__ dst, int* __restrict__ deg, int E) {
    int e = blockIdx.x * blockDim.x + threadIdx.x;
    if (e < E) atomicAdd(&deg[dst[e]], 1);
}

// ---- hierarchical scan: A (per-block local exclusive scan), B (scan block sums), C (apply) ----
__global__ __launch_bounds__(1024) void scanA_kernel(const int* __restrict__ deg,
                                                     int* __restrict__ excl,
                                                     int* __restrict__ bsum, int N) {
    const int tid = threadIdx.x, lane = tid & 63, wid = tid >> 6;
    const int i = blockIdx.x * 1024 + tid;
    int v = (i < N) ? deg[i] : 0;
    int s = v;
#pragma unroll
    for (int off = 1; off < 64; off <<= 1) {
        int t = __shfl_up(s, off, 64);
        if (lane >= off) s += t;
    }
    __shared__ int wtot[16], woff[16];
    if (lane == 63) wtot[wid] = s;
    __syncthreads();
    if (wid == 0 && lane < 16) {
        int t = wtot[lane];
        int ss = t;
#pragma unroll
        for (int off = 1; off < 16; off <<= 1) {
            int u = __shfl_up(ss, off, 64);
            if (lane >= off) ss += u;
        }
        woff[lane] = ss - t;
        if (lane == 15) bsum[blockIdx.x] = ss;
    }
    __syncthreads();
    if (i < N) excl[i] = woff[wid] + (s - v);
}

__global__ void scanB_kernel(int* __restrict__ bsum, int nb) {
    int lane = threadIdx.x;           // 64 threads, nb <= 64
    int v = (lane < nb) ? bsum[lane] : 0;
    int s = v;
#pragma unroll
    for (int off = 1; off < 64; off <<= 1) {
        int t = __shfl_up(s, off, 64);
        if (lane >= off) s += t;
    }
    if (lane < nb) bsum[lane] = s - v;   // exclusive
}

__global__ __launch_bounds__(1024) void scanC_kernel(const int* __restrict__ excl,
                                                     const int* __restrict__ bsum,
                                                     const int* __restrict__ deg,
                                                     int* __restrict__ row_start,
                                                     int* __restrict__ cursor,
                                                     float* __restrict__ inv_deg, int N, int E) {
    int i = blockIdx.x * 1024 + threadIdx.x;
    if (i < N) {
        int e = excl[i] + bsum[blockIdx.x];
        row_start[i] = e;
        cursor[i] = e;
        int d = deg[i];
        inv_deg[i] = (d > 0) ? 1.0f / (float)d : 0.0f;
    }
    if (i == 0) row_start[N] = E;
}

// ---- scatter edges into CSR slots (nontemporal store: fight 64B-line write amplification) ----
__global__ void fill_kernel(const int* __restrict__ src, const int* __restrict__ dst,
                            int* __restrict__ cursor, int* __restrict__ csr, int E) {
    int e = blockIdx.x * blockDim.x + threadIdx.x;
    if (e < E) {
        int p = atomicAdd(&cursor[dst[e]], 1);
        __builtin_nontemporal_store(src[e], &csr[p]);
    }
}

// ---- fused layer: gather-mean into LDS Z, then [h|neigh] @ W^T + relu + L2-norm ----
// Block = 256 (4 waves), 32 nodes/block, 8 nodes/wave; lane = output dim for matmul,
// lane = feature dim for gather. NOT in-place safe (gathers read arbitrary rows) ->
// caller must ping-pong buffers.
__global__ __launch_bounds__(256) void layer_kernel(
    const float* __restrict__ h, const int* __restrict__ row_start,
    const int* __restrict__ csr, const float* __restrict__ inv_deg,
    const float* __restrict__ W, float* __restrict__ out, int N) {
    __shared__ float4 Wl[64 * 32];     // 32 KB: W[row][j4] at row*32 + (j4 ^ (row&7))
    __shared__ float4 Z4v[32 * 32];    // 16 KB: 32 nodes x 128 floats
    float* Zf = (float*)Z4v;
    const int tid = threadIdx.x;
    const int lane = tid & 63;
    const int w = tid >> 6;
    const int base = blockIdx.x * 32;
    const int nb = w * 8;              // this wave's 8 nodes

    // stage W (swizzled) — 2048 float4, coalesced
    for (int t = tid; t < 2048; t += 256) {
        int row = t >> 5;
        int j4 = t & 31;
        Wl[row * 32 + (j4 ^ (row & 7))] = ((const float4*)W)[t];
    }

    // gather phase: wave computes mean for its 8 nodes, writes [h | mean] into Z
    for (int n = 0; n < 8; ++n) {
        int node = base + nb + n;      // wave-uniform
        if (node >= N) break;
        int nu = __builtin_amdgcn_readfirstlane(node);
        int rs = row_start[nu];
        int re = row_start[nu + 1];
        float a0 = 0.f, a1 = 0.f, a2 = 0.f, a3 = 0.f;
        float a4 = 0.f, a5 = 0.f, a6 = 0.f, a7 = 0.f;
        int j = rs;
        while (j < re) {
            int take = re - j;
            if (take > 64) take = 64;
            int idx = (lane < take) ? csr[j + lane] : 0;   // one coalesced index load
            int i = 0;
            for (; i + 8 <= take; i += 8) {
                int s0 = __builtin_amdgcn_readlane(idx, i + 0);
                int s1 = __builtin_amdgcn_readlane(idx, i + 1);
                int s2 = __builtin_amdgcn_readlane(idx, i + 2);
                int s3 = __builtin_amdgcn_readlane(idx, i + 3);
                int s4 = __builtin_amdgcn_readlane(idx, i + 4);
                int s5 = __builtin_amdgcn_readlane(idx, i + 5);
                int s6 = __builtin_amdgcn_readlane(idx, i + 6);
                int s7 = __builtin_amdgcn_readlane(idx, i + 7);
                a0 += h[(long long)s0 * HD + lane];
                a1 += h[(long long)s1 * HD + lane];
                a2 += h[(long long)s2 * HD + lane];
                a3 += h[(long long)s3 * HD + lane];
                a4 += h[(long long)s4 * HD + lane];
                a5 += h[(long long)s5 * HD + lane];
                a6 += h[(long long)s6 * HD + lane];
                a7 += h[(long long)s7 * HD + lane];
            }
            for (; i < take; ++i) {
                int s0 = __builtin_amdgcn_readlane(idx, i);
                a0 += h[(long long)s0 * HD + lane];
            }
            j += take;
        }
        float m = (((a0 + a1) + (a2 + a3)) + ((a4 + a5) + (a6 + a7))) * inv_deg[nu];
        Zf[(nb + n) * 128 + lane] = h[(long long)nu * HD + lane];
        Zf[(nb + n) * 128 + 64 + lane] = m;
    }
    __syncthreads();

    // matmul: lane = output dim; unroll capped (round-3 lesson: avoid spill)
    float acc[8] = {0.f, 0.f, 0.f, 0.f, 0.f, 0.f, 0.f, 0.f};
#pragma unroll 2
    for (int j4 = 0; j4 < 32; ++j4) {
        float4 wv = Wl[lane * 32 + (j4 ^ (lane & 7))];
#pragma unroll
        for (int n = 0; n < 8; ++n) {
            float4 z = Z4v[(nb + n) * 32 + j4];   // wave-uniform broadcast
            acc[n] = fmaf(z.x, wv.x, fmaf(z.y, wv.y, fmaf(z.z, wv.z, fmaf(z.w, wv.w, acc[n]))));
        }
    }

    // epilogue: relu + cross-lane L2 norm per node + store
#pragma unroll
    for (int n = 0; n < 8; ++n) {
        float v = fmaxf(acc[n], 0.f);
        float sq = v * v;
#pragma unroll
        for (int off = 32; off >= 1; off >>= 1) sq += __shfl_xor(sq, off, 64);
        float sc = 1.f / fmaxf(sqrtf(sq), 1e-12f);
        int node = base + nb + n;
        if (node < N) out[(long long)node * HD + lane] = v * sc;
    }
}

extern "C" void kernel_launch(void* const* d_in, const int* in_sizes, int n_in,
                              void* d_out, int out_size, void* d_ws, size_t ws_size,
                              hipStream_t stream) {
    const float* x    = (const float*)d_in[0];
    const float* W    = (const float*)d_in[1];
    const int*   esrc = (const int*)d_in[2];
    const int*   edst = (const int*)d_in[3];
    float* out = (float*)d_out;

    const int N = in_sizes[0] / HD;
    const int E = in_sizes[2];
    const int DEPTH = in_sizes[1] / (HD * 2 * HD);
    const int NB = (N + 1023) / 1024;

    // workspace: deg[N] | excl[N] | bsum[64] | row_start[N+1] | cursor[N] | inv_deg[N] | csr[E] | h1[N*HD]
    auto align256 = [](size_t v) { return (v + 255) & ~(size_t)255; };
    char* ws = (char*)d_ws;
    int*   deg       = (int*)ws;    ws += align256((size_t)N * 4);
    int*   excl      = (int*)ws;    ws += align256((size_t)N * 4);
    int*   bsum      = (int*)ws;    ws += align256(64 * 4);
    int*   row_start = (int*)ws;    ws += align256((size_t)(N + 1) * 4);
    int*   cursor    = (int*)ws;    ws += align256((size_t)N * 4);
    float* inv_deg   = (float*)ws;  ws += align256((size_t)N * 4);
    int*   csr       = (int*)ws;    ws += align256((size_t)E * 4);
    float* h1        = (float*)ws;

    hipMemsetAsync(deg, 0, (size_t)N * sizeof(int), stream);
    deg_kernel<<<(E + 255) / 256, 256, 0, stream>>>(edst, deg, E);
    scanA_kernel<<<NB, 1024, 0, stream>>>(deg, excl, bsum, N);
    scanB_kernel<<<1, 64, 0, stream>>>(bsum, NB);
    scanC_kernel<<<NB, 1024, 0, stream>>>(excl, bsum, deg, row_start, cursor, inv_deg, N, E);
    fill_kernel<<<(E + 255) / 256, 256, 0, stream>>>(esrc, edst, cursor, csr, E);

    // ping-pong: layer reads arbitrary rows (gather) while writing its own -> src != dst
    const float* h_in = x;
    for (int k = 0; k < DEPTH; ++k) {
        float* dst = (((DEPTH - 1 - k) & 1) == 0) ? out : h1;
        layer_kernel<<<(N + 31) / 32, 256, 0, stream>>>(h_in, row_start, csr, inv_deg,
                                                        W + (size_t)k * HD * 2 * HD, dst, N);
        h_in = dst;
    }
}

// Round 6
// 213.993 us; speedup vs baseline: 1.3490x; 1.3490x over previous
//
#include <hip/hip_runtime.h>

#define HD 64   // hidden dim D

// ---- degree histogram, dst-range partitioned: group g = blockIdx&7 owns dst slice
// [g*N/8,(g+1)*N/8) so deg lines stay in ONE XCD's L2 (no cross-XCD atomic line thrash).
__global__ void deg_part_kernel(const int* __restrict__ dst, int* __restrict__ deg,
                                int E, int N) {
    const int g = blockIdx.x & 7;
    const int per = (N + 7) / 8;
    const int lo = g * per;
    const int hi = min(N, lo + per);
    const int nb = gridDim.x >> 3;
    const int b = blockIdx.x >> 3;
    for (int e = b * blockDim.x + threadIdx.x; e < E; e += nb * blockDim.x) {
        int d = dst[e];
        if (d >= lo && d < hi) atomicAdd(&deg[d], 1);
    }
}

// ---- per-block local exclusive scan of deg ----
__global__ __launch_bounds__(1024) void scanA_kernel(const int* __restrict__ deg,
                                                     int* __restrict__ excl,
                                                     int* __restrict__ bsum, int N) {
    const int tid = threadIdx.x, lane = tid & 63, wid = tid >> 6;
    const int i = blockIdx.x * 1024 + tid;
    int v = (i < N) ? deg[i] : 0;
    int s = v;
#pragma unroll
    for (int off = 1; off < 64; off <<= 1) {
        int t = __shfl_up(s, off, 64);
        if (lane >= off) s += t;
    }
    __shared__ int wtot[16], woff[16];
    if (lane == 63) wtot[wid] = s;
    __syncthreads();
    if (wid == 0 && lane < 16) {
        int t = wtot[lane];
        int ss = t;
#pragma unroll
        for (int off = 1; off < 16; off <<= 1) {
            int u = __shfl_up(ss, off, 64);
            if (lane >= off) ss += u;
        }
        woff[lane] = ss - t;
        if (lane == 15) bsum[blockIdx.x] = ss;
    }
    __syncthreads();
    if (i < N) excl[i] = woff[wid] + (s - v);
}

// ---- apply: scans bsum (NB<=64) in-wave per block (scanB folded in) ----
__global__ __launch_bounds__(1024) void scanC_kernel(const int* __restrict__ excl,
                                                     const int* __restrict__ bsum,
                                                     const int* __restrict__ deg,
                                                     int* __restrict__ row_start,
                                                     int* __restrict__ cursor,
                                                     float* __restrict__ inv_deg,
                                                     int N, int E, int NB) {
    __shared__ int boff_s;
    const int tid = threadIdx.x;
    if (tid < 64) {
        int lane = tid;
        int v = (lane < NB) ? bsum[lane] : 0;
        int s = v;
#pragma unroll
        for (int off = 1; off < 64; off <<= 1) {
            int t = __shfl_up(s, off, 64);
            if (lane >= off) s += t;
        }
        if (lane == (int)blockIdx.x) boff_s = s - v;   // exclusive prefix for this block
    }
    __syncthreads();
    const int boff = boff_s;
    int i = blockIdx.x * 1024 + tid;
    if (i < N) {
        int e = excl[i] + boff;
        row_start[i] = e;
        cursor[i] = e;
        int d = deg[i];
        inv_deg[i] = (d > 0) ? 1.0f / (float)d : 0.0f;
    }
    if (blockIdx.x == 0 && tid == 0) row_start[N] = E;
}

// ---- CSR fill, dst-range partitioned (same scheme as deg): group g only places
// edges whose dst lies in its slice -> csr/cursor lines are XCD-local, dirty lines
// accumulate ~16 stores in L2 before ONE writeback (was: 1 writeback per 4B store).
__global__ void fill_part_kernel(const int* __restrict__ src, const int* __restrict__ dst,
                                 int* __restrict__ cursor, int* __restrict__ csr,
                                 int E, int N) {
    const int g = blockIdx.x & 7;
    const int per = (N + 7) / 8;
    const int lo = g * per;
    const int hi = min(N, lo + per);
    const int nb = gridDim.x >> 3;
    const int b = blockIdx.x >> 3;
    for (int e = b * blockDim.x + threadIdx.x; e < E; e += nb * blockDim.x) {
        int d = dst[e];
        if (d >= lo && d < hi) {
            int p = atomicAdd(&cursor[d], 1);
            csr[p] = src[e];
        }
    }
}

// ---- aggregate: wave per node, lane = feature dim; mean of neighbor rows ----
// Lean VGPR, no LDS -> 8 waves/SIMD for latency hiding (round-5 lesson: do NOT
// fuse this with the LDS-heavy matmul).
__global__ __launch_bounds__(256, 8) void agg_kernel(
    const float* __restrict__ h, const int* __restrict__ row_start,
    const int* __restrict__ csr, const float* __restrict__ inv_deg,
    float* __restrict__ neigh, int N) {
    const int wv = (blockIdx.x * blockDim.x + threadIdx.x) >> 6;
    const int lane = threadIdx.x & 63;
    if (wv >= N) return;
    const int rs = row_start[wv];
    const int re = row_start[wv + 1];

    float a0 = 0.f, a1 = 0.f, a2 = 0.f, a3 = 0.f;
    float a4 = 0.f, a5 = 0.f, a6 = 0.f, a7 = 0.f;
    int j = rs;
    while (j < re) {
        int take = re - j;
        if (take > 64) take = 64;
        int idx = (lane < take) ? csr[j + lane] : 0;   // one coalesced index load
        int i = 0;
        for (; i + 8 <= take; i += 8) {
            int s0 = __builtin_amdgcn_readlane(idx, i + 0);
            int s1 = __builtin_amdgcn_readlane(idx, i + 1);
            int s2 = __builtin_amdgcn_readlane(idx, i + 2);
            int s3 = __builtin_amdgcn_readlane(idx, i + 3);
            int s4 = __builtin_amdgcn_readlane(idx, i + 4);
            int s5 = __builtin_amdgcn_readlane(idx, i + 5);
            int s6 = __builtin_amdgcn_readlane(idx, i + 6);
            int s7 = __builtin_amdgcn_readlane(idx, i + 7);
            a0 += h[(long long)s0 * HD + lane];
            a1 += h[(long long)s1 * HD + lane];
            a2 += h[(long long)s2 * HD + lane];
            a3 += h[(long long)s3 * HD + lane];
            a4 += h[(long long)s4 * HD + lane];
            a5 += h[(long long)s5 * HD + lane];
            a6 += h[(long long)s6 * HD + lane];
            a7 += h[(long long)s7 * HD + lane];
        }
        for (; i < take; ++i) {
            int s0 = __builtin_amdgcn_readlane(idx, i);
            a0 += h[(long long)s0 * HD + lane];
        }
        j += take;
    }
    float m = (((a0 + a1) + (a2 + a3)) + ((a4 + a5) + (a6 + a7))) * inv_deg[wv];
    neigh[(long long)wv * HD + lane] = m;
}

// ---- GEMM + relu + L2-norm: out = l2norm(relu([h|neigh] @ W^T)) ----
// Block = 256 (4 waves), 32 nodes/block, 8 nodes/wave; lane = output dim.
// W in XOR-swizzled LDS; j4 unroll capped at 2 (round-3 lesson: avoid spill).
// In-place safe: block reads only its own 32 rows of h before writing them.
__global__ __launch_bounds__(256) void gemm_kernel(
    const float* __restrict__ h, const float* __restrict__ neigh,
    const float* __restrict__ W, float* __restrict__ out, int N) {
    __shared__ float4 Wl[64 * 32];     // 32 KB
    __shared__ float4 Z[32 * 32];      // 16 KB
    const int tid = threadIdx.x;
    const int lane = tid & 63;
    const int w = tid >> 6;
    const int base = blockIdx.x * 32;

    for (int t = tid; t < 2048; t += 256) {
        int row = t >> 5;
        int j4 = t & 31;
        Wl[row * 32 + (j4 ^ (row & 7))] = ((const float4*)W)[t];
    }
    for (int t = tid; t < 512; t += 256) {
        int n = t >> 4;
        int j4 = t & 15;
        int node = base + n;
        if (node < N) {
            Z[n * 32 + j4]      = ((const float4*)&h[(long long)node * HD])[j4];
            Z[n * 32 + 16 + j4] = ((const float4*)&neigh[(long long)node * HD])[j4];
        }
    }
    __syncthreads();

    float acc[8] = {0.f, 0.f, 0.f, 0.f, 0.f, 0.f, 0.f, 0.f};
    const int nb = w * 8;
#pragma unroll 2
    for (int j4 = 0; j4 < 32; ++j4) {
        float4 wv = Wl[lane * 32 + (j4 ^ (lane & 7))];
#pragma unroll
        for (int n = 0; n < 8; ++n) {
            float4 z = Z[(nb + n) * 32 + j4];   // wave-uniform broadcast
            acc[n] = fmaf(z.x, wv.x, fmaf(z.y, wv.y, fmaf(z.z, wv.z, fmaf(z.w, wv.w, acc[n]))));
        }
    }

#pragma unroll
    for (int n = 0; n < 8; ++n) {
        float v = fmaxf(acc[n], 0.f);
        float sq = v * v;
#pragma unroll
        for (int off = 32; off >= 1; off >>= 1) sq += __shfl_xor(sq, off, 64);
        float sc = 1.f / fmaxf(sqrtf(sq), 1e-12f);
        int node = base + nb + n;
        if (node < N) out[(long long)node * HD + lane] = v * sc;
    }
}

extern "C" void kernel_launch(void* const* d_in, const int* in_sizes, int n_in,
                              void* d_out, int out_size, void* d_ws, size_t ws_size,
                              hipStream_t stream) {
    const float* x    = (const float*)d_in[0];
    const float* W    = (const float*)d_in[1];
    const int*   esrc = (const int*)d_in[2];
    const int*   edst = (const int*)d_in[3];
    float* out = (float*)d_out;

    const int N = in_sizes[0] / HD;
    const int E = in_sizes[2];
    const int DEPTH = in_sizes[1] / (HD * 2 * HD);
    const int NB = (N + 1023) / 1024;

    // workspace: deg[N] | excl[N] | bsum[64] | row_start[N+1] | cursor[N] | inv_deg[N] | csr[E] | neigh[N*HD]
    auto align256 = [](size_t v) { return (v + 255) & ~(size_t)255; };
    char* ws = (char*)d_ws;
    int*   deg       = (int*)ws;    ws += align256((size_t)N * 4);
    int*   excl      = (int*)ws;    ws += align256((size_t)N * 4);
    int*   bsum      = (int*)ws;    ws += align256(64 * 4);
    int*   row_start = (int*)ws;    ws += align256((size_t)(N + 1) * 4);
    int*   cursor    = (int*)ws;    ws += align256((size_t)N * 4);
    float* inv_deg   = (float*)ws;  ws += align256((size_t)N * 4);
    int*   csr       = (int*)ws;    ws += align256((size_t)E * 4);
    float* neigh     = (float*)ws;

    hipMemsetAsync(deg, 0, (size_t)N * sizeof(int), stream);
    deg_part_kernel<<<2048, 256, 0, stream>>>(edst, deg, E, N);
    scanA_kernel<<<NB, 1024, 0, stream>>>(deg, excl, bsum, N);
    scanC_kernel<<<NB, 1024, 0, stream>>>(excl, bsum, deg, row_start, cursor, inv_deg, N, E, NB);
    fill_part_kernel<<<2048, 256, 0, stream>>>(esrc, edst, cursor, csr, E, N);

    const float* h_in = x;
    for (int k = 0; k < DEPTH; ++k) {
        agg_kernel<<<(N * 64 + 255) / 256, 256, 0, stream>>>(h_in, row_start, csr, inv_deg, neigh, N);
        gemm_kernel<<<(N + 31) / 32, 256, 0, stream>>>(h_in, neigh,
                                                       W + (size_t)k * HD * 2 * HD, out, N);
        h_in = out;   // gemm is in-place safe
    }
}

// Round 7
// 213.417 us; speedup vs baseline: 1.3526x; 1.0027x over previous
//
#include <hip/hip_runtime.h>

#define HD 64   // hidden dim D

// ---- fast zero (replaces rocclr fillBuffer which ran latency-bound at 44us) ----
__global__ void zero_kernel(int4* __restrict__ p, int n4) {
    int i = blockIdx.x * blockDim.x + threadIdx.x;
    if (i < n4) p[i] = int4{0, 0, 0, 0};
}

// ---- degree histogram, dst-range partitioned: group g = blockIdx&7 owns dst slice
// [g*N/8,(g+1)*N/8) so deg lines stay in ONE XCD's L2 (no cross-XCD atomic line thrash).
__global__ void deg_part_kernel(const int* __restrict__ dst, int* __restrict__ deg,
                                int E, int N) {
    const int g = blockIdx.x & 7;
    const int per = (N + 7) / 8;
    const int lo = g * per;
    const int hi = min(N, lo + per);
    const int nb = gridDim.x >> 3;
    const int b = blockIdx.x >> 3;
    for (int e = b * blockDim.x + threadIdx.x; e < E; e += nb * blockDim.x) {
        int d = dst[e];
        if (d >= lo && d < hi) atomicAdd(&deg[d], 1);
    }
}

// ---- per-block local exclusive scan of deg ----
__global__ __launch_bounds__(1024) void scanA_kernel(const int* __restrict__ deg,
                                                     int* __restrict__ excl,
                                                     int* __restrict__ bsum, int N) {
    const int tid = threadIdx.x, lane = tid & 63, wid = tid >> 6;
    const int i = blockIdx.x * 1024 + tid;
    int v = (i < N) ? deg[i] : 0;
    int s = v;
#pragma unroll
    for (int off = 1; off < 64; off <<= 1) {
        int t = __shfl_up(s, off, 64);
        if (lane >= off) s += t;
    }
    __shared__ int wtot[16], woff[16];
    if (lane == 63) wtot[wid] = s;
    __syncthreads();
    if (wid == 0 && lane < 16) {
        int t = wtot[lane];
        int ss = t;
#pragma unroll
        for (int off = 1; off < 16; off <<= 1) {
            int u = __shfl_up(ss, off, 64);
            if (lane >= off) ss += u;
        }
        woff[lane] = ss - t;
        if (lane == 15) bsum[blockIdx.x] = ss;
    }
    __syncthreads();
    if (i < N) excl[i] = woff[wid] + (s - v);
}

// ---- apply: scans bsum (NB<=64) in-wave per block (scanB folded in) ----
__global__ __launch_bounds__(1024) void scanC_kernel(const int* __restrict__ excl,
                                                     const int* __restrict__ bsum,
                                                     const int* __restrict__ deg,
                                                     int* __restrict__ row_start,
                                                     int* __restrict__ cursor,
                                                     float* __restrict__ inv_deg,
                                                     int N, int E, int NB) {
    __shared__ int boff_s;
    const int tid = threadIdx.x;
    if (tid < 64) {
        int lane = tid;
        int v = (lane < NB) ? bsum[lane] : 0;
        int s = v;
#pragma unroll
        for (int off = 1; off < 64; off <<= 1) {
            int t = __shfl_up(s, off, 64);
            if (lane >= off) s += t;
        }
        if (lane == (int)blockIdx.x) boff_s = s - v;   // exclusive prefix for this block
    }
    __syncthreads();
    const int boff = boff_s;
    int i = blockIdx.x * 1024 + tid;
    if (i < N) {
        int e = excl[i] + boff;
        row_start[i] = e;
        cursor[i] = e;
        int d = deg[i];
        inv_deg[i] = (d > 0) ? 1.0f / (float)d : 0.0f;
    }
    if (blockIdx.x == 0 && tid == 0) row_start[N] = E;
}

// ---- CSR fill, dst-range partitioned (same scheme as deg): group g only places
// edges whose dst lies in its slice -> csr/cursor lines are XCD-local, dirty lines
// accumulate ~16 stores in L2 before ONE writeback (was: 1 writeback per 4B store).
__global__ void fill_part_kernel(const int* __restrict__ src, const int* __restrict__ dst,
                                 int* __restrict__ cursor, int* __restrict__ csr,
                                 int E, int N) {
    const int g = blockIdx.x & 7;
    const int per = (N + 7) / 8;
    const int lo = g * per;
    const int hi = min(N, lo + per);
    const int nb = gridDim.x >> 3;
    const int b = blockIdx.x >> 3;
    for (int e = b * blockDim.x + threadIdx.x; e < E; e += nb * blockDim.x) {
        int d = dst[e];
        if (d >= lo && d < hi) {
            int p = atomicAdd(&cursor[d], 1);
            csr[p] = src[e];
        }
    }
}

// ---- aggregate: wave per node, lane = feature dim; mean of neighbor rows ----
// Lean VGPR, no LDS -> 8 waves/SIMD for latency hiding (round-5 lesson: do NOT
// fuse this with the LDS-heavy matmul).
__global__ __launch_bounds__(256, 8) void agg_kernel(
    const float* __restrict__ h, const int* __restrict__ row_start,
    const int* __restrict__ csr, const float* __restrict__ inv_deg,
    float* __restrict__ neigh, int N) {
    const int wv = (blockIdx.x * blockDim.x + threadIdx.x) >> 6;
    const int lane = threadIdx.x & 63;
    if (wv >= N) return;
    const int rs = row_start[wv];
    const int re = row_start[wv + 1];

    float a0 = 0.f, a1 = 0.f, a2 = 0.f, a3 = 0.f;
    float a4 = 0.f, a5 = 0.f, a6 = 0.f, a7 = 0.f;
    int j = rs;
    while (j < re) {
        int take = re - j;
        if (take > 64) take = 64;
        int idx = (lane < take) ? csr[j + lane] : 0;   // one coalesced index load
        int i = 0;
        for (; i + 8 <= take; i += 8) {
            int s0 = __builtin_amdgcn_readlane(idx, i + 0);
            int s1 = __builtin_amdgcn_readlane(idx, i + 1);
            int s2 = __builtin_amdgcn_readlane(idx, i + 2);
            int s3 = __builtin_amdgcn_readlane(idx, i + 3);
            int s4 = __builtin_amdgcn_readlane(idx, i + 4);
            int s5 = __builtin_amdgcn_readlane(idx, i + 5);
            int s6 = __builtin_amdgcn_readlane(idx, i + 6);
            int s7 = __builtin_amdgcn_readlane(idx, i + 7);
            a0 += h[(long long)s0 * HD + lane];
            a1 += h[(long long)s1 * HD + lane];
            a2 += h[(long long)s2 * HD + lane];
            a3 += h[(long long)s3 * HD + lane];
            a4 += h[(long long)s4 * HD + lane];
            a5 += h[(long long)s5 * HD + lane];
            a6 += h[(long long)s6 * HD + lane];
            a7 += h[(long long)s7 * HD + lane];
        }
        for (; i < take; ++i) {
            int s0 = __builtin_amdgcn_readlane(idx, i);
            a0 += h[(long long)s0 * HD + lane];
        }
        j += take;
    }
    float m = (((a0 + a1) + (a2 + a3)) + ((a4 + a5) + (a6 + a7))) * inv_deg[wv];
    neigh[(long long)wv * HD + lane] = m;
}

// ---- GEMM + relu + L2-norm: out = l2norm(relu([h|neigh] @ W^T)) ----
// Block = 256 (4 waves), 32 nodes/block, 8 nodes/wave; lane = output dim.
// W in XOR-swizzled LDS; j4 unroll capped at 2 (round-3 lesson: avoid spill).
// In-place safe: block reads only its own 32 rows of h before writing them.
__global__ __launch_bounds__(256) void gemm_kernel(
    const float* __restrict__ h, const float* __restrict__ neigh,
    const float* __restrict__ W, float* __restrict__ out, int N) {
    __shared__ float4 Wl[64 * 32];     // 32 KB
    __shared__ float4 Z[32 * 32];      // 16 KB
    const int tid = threadIdx.x;
    const int lane = tid & 63;
    const int w = tid >> 6;
    const int base = blockIdx.x * 32;

    for (int t = tid; t < 2048; t += 256) {
        int row = t >> 5;
        int j4 = t & 31;
        Wl[row * 32 + (j4 ^ (row & 7))] = ((const float4*)W)[t];
    }
    for (int t = tid; t < 512; t += 256) {
        int n = t >> 4;
        int j4 = t & 15;
        int node = base + n;
        if (node < N) {
            Z[n * 32 + j4]      = ((const float4*)&h[(long long)node * HD])[j4];
            Z[n * 32 + 16 + j4] = ((const float4*)&neigh[(long long)node * HD])[j4];
        }
    }
    __syncthreads();

    float acc[8] = {0.f, 0.f, 0.f, 0.f, 0.f, 0.f, 0.f, 0.f};
    const int nb = w * 8;
#pragma unroll 2
    for (int j4 = 0; j4 < 32; ++j4) {
        float4 wv = Wl[lane * 32 + (j4 ^ (lane & 7))];
#pragma unroll
        for (int n = 0; n < 8; ++n) {
            float4 z = Z[(nb + n) * 32 + j4];   // wave-uniform broadcast
            acc[n] = fmaf(z.x, wv.x, fmaf(z.y, wv.y, fmaf(z.z, wv.z, fmaf(z.w, wv.w, acc[n]))));
        }
    }

#pragma unroll
    for (int n = 0; n < 8; ++n) {
        float v = fmaxf(acc[n], 0.f);
        float sq = v * v;
#pragma unroll
        for (int off = 32; off >= 1; off >>= 1) sq += __shfl_xor(sq, off, 64);
        float sc = 1.f / fmaxf(sqrtf(sq), 1e-12f);
        int node = base + nb + n;
        if (node < N) out[(long long)node * HD + lane] = v * sc;
    }
}

extern "C" void kernel_launch(void* const* d_in, const int* in_sizes, int n_in,
                              void* d_out, int out_size, void* d_ws, size_t ws_size,
                              hipStream_t stream) {
    const float* x    = (const float*)d_in[0];
    const float* W    = (const float*)d_in[1];
    const int*   esrc = (const int*)d_in[2];
    const int*   edst = (const int*)d_in[3];
    float* out = (float*)d_out;

    const int N = in_sizes[0] / HD;
    const int E = in_sizes[2];
    const int DEPTH = in_sizes[1] / (HD * 2 * HD);
    const int NB = (N + 1023) / 1024;

    // workspace: deg[N(+pad to 4)] | excl[N] | bsum[64] | row_start[N+1] | cursor[N] | inv_deg[N] | csr[E] | neigh[N*HD]
    auto align256 = [](size_t v) { return (v + 255) & ~(size_t)255; };
    char* ws = (char*)d_ws;
    int*   deg       = (int*)ws;    ws += align256((size_t)(N + 4) * 4);
    int*   excl      = (int*)ws;    ws += align256((size_t)N * 4);
    int*   bsum      = (int*)ws;    ws += align256(64 * 4);
    int*   row_start = (int*)ws;    ws += align256((size_t)(N + 1) * 4);
    int*   cursor    = (int*)ws;    ws += align256((size_t)N * 4);
    float* inv_deg   = (float*)ws;  ws += align256((size_t)N * 4);
    int*   csr       = (int*)ws;    ws += align256((size_t)E * 4);
    float* neigh     = (float*)ws;

    // fast zero of deg (rocclr fillBuffer ran at 4.5 GB/s / 44us -- round-6 counter evidence)
    int n4 = (N + 3) / 4;
    zero_kernel<<<(n4 + 255) / 256, 256, 0, stream>>>((int4*)deg, n4);
    deg_part_kernel<<<2048, 256, 0, stream>>>(edst, deg, E, N);
    scanA_kernel<<<NB, 1024, 0, stream>>>(deg, excl, bsum, N);
    scanC_kernel<<<NB, 1024, 0, stream>>>(excl, bsum, deg, row_start, cursor, inv_deg, N, E, NB);
    fill_part_kernel<<<2048, 256, 0, stream>>>(esrc, edst, cursor, csr, E, N);

    const float* h_in = x;
    for (int k = 0; k < DEPTH; ++k) {
        agg_kernel<<<(N * 64 + 255) / 256, 256, 0, stream>>>(h_in, row_start, csr, inv_deg, neigh, N);
        gemm_kernel<<<(N + 31) / 32, 256, 0, stream>>>(h_in, neigh,
                                                       W + (size_t)k * HD * 2 * HD, out, N);
        h_in = out;   // gemm is in-place safe
    }
}